// Round 13
// baseline (639.617 us; speedup 1.0000x reference)
//
#include <hip/hip_runtime.h>
#include <hip/hip_fp16.h>

typedef _Float16 half8 __attribute__((ext_vector_type(8)));
typedef _Float16 half4 __attribute__((ext_vector_type(4)));
typedef float floatx4 __attribute__((ext_vector_type(4)));

#define EPS 1e-5f

__device__ inline float roundstore(_Float16* p, float v){
    _Float16 h = (_Float16)v; *p = h; return (float)h; }

// ---------------------------------------------------------------------------
// conv1 stats: conv1 (1->16ch) from x (NCHW fp32), per-channel sum/sumsq.
// ---------------------------------------------------------------------------
__global__ __launch_bounds__(256)
void conv1_stats_kernel(const float* __restrict__ x, const float* __restrict__ w1,
                        float* __restrict__ stats_out, int H, int W)
{
    __shared__ float xt[10][34];
    __shared__ float wred[4][32];
    const int t = threadIdx.x;
    const int n = blockIdx.z;
    const int tx = t & 31, ty = t >> 5;
    const int ox = blockIdx.x * 32 + tx;
    const int x0 = blockIdx.x * 32 - 1;

    float racc[16], rqacc[16];
    #pragma unroll
    for (int oc = 0; oc < 16; oc++) { racc[oc] = 0.0f; rqacc[oc] = 0.0f; }

    for (int yt = 0; yt < 16; yt++) {
        const int ybase = (blockIdx.y * 16 + yt) * 8;
        const int oy = ybase + ty;
        const int y0 = ybase - 1;
        __syncthreads();
        for (int idx = t; idx < 340; idx += 256) {
            int r = idx / 34, c = idx - r * 34;
            int gy = y0 + r, gx = x0 + c;
            xt[r][c] = ((unsigned)gy < (unsigned)H && (unsigned)gx < (unsigned)W)
                     ? x[((size_t)n * H + gy) * W + gx] : 0.0f;
        }
        __syncthreads();
        if (oy < H && ox < W) {
            float win[9];
            #pragma unroll
            for (int dy = 0; dy < 3; dy++)
                #pragma unroll
                for (int dx = 0; dx < 3; dx++) win[dy * 3 + dx] = xt[ty + dy][tx + dx];
            #pragma unroll
            for (int oc = 0; oc < 16; oc++) {
                float v = 0.0f;
                #pragma unroll
                for (int k = 0; k < 9; k++) v = fmaf(w1[oc * 9 + k], win[k], v);
                racc[oc] += v; rqacc[oc] += v * v;
            }
        }
    }

    #pragma unroll
    for (int oc = 0; oc < 16; oc++) {
        float a = racc[oc], b = rqacc[oc];
        for (int off = 32; off; off >>= 1) {
            a += __shfl_xor(a, off, 64);
            b += __shfl_xor(b, off, 64);
        }
        racc[oc] = a; rqacc[oc] = b;
    }
    const int wave = t >> 6;
    if ((t & 63) == 0) {
        #pragma unroll
        for (int oc = 0; oc < 16; oc++) {
            wred[wave][oc] = racc[oc];
            wred[wave][16 + oc] = rqacc[oc];
        }
    }
    __syncthreads();
    if (t < 32) {
        float v = wred[0][t] + wred[1][t] + wred[2][t] + wred[3][t];
        atomicAdd(&stats_out[(t < 16 ? 0 : 80) + (t & 15)], v);
    }
}

// ---------------------------------------------------------------------------
// Fold BN1 into conv1 weights: w1f = sc1*w1, b1f = bi1. One block.
// ---------------------------------------------------------------------------
__global__ void fold_w1_kernel(const float* __restrict__ w1, const float* __restrict__ gb1,
                               const float* __restrict__ stats1, float inv_n,
                               float* __restrict__ w1f, float* __restrict__ b1f)
{
    __shared__ float sc[16], bi[16];
    const int t = threadIdx.x;
    if (t < 16) {
        float s = stats1[t], sq = stats1[80 + t];
        float mu = s * inv_n;
        float var = fmaxf(sq * inv_n - mu * mu, 0.0f);
        float scl = gb1[t] * rsqrtf(var + EPS);
        sc[t] = scl;
        bi[t] = gb1[16 + t] - mu * scl;
    }
    __syncthreads();
    if (t < 144) w1f[t] = w1[t] * sc[t / 9];
    if (t < 16)  b1f[t] = bi[t];
}

// ---------------------------------------------------------------------------
// Weight pre-pack into exact MFMA B-fragment lane order (validated).
// ---------------------------------------------------------------------------
__device__ inline void pack_one(const float* __restrict__ w, _Float16* __restrict__ out,
                                int CIN, int NT, int e)
{
    int j    = e & 7;
    int lane = (e >> 3) & 63;
    int frag = e >> 9;
    int nt = frag % NT;
    int tp = (frag / NT) % 5;
    int cc = frag / (NT * 5);
    int k   = ((lane >> 4) << 3) + j;
    int tap = 2 * tp + (k >> 4);
    int ci  = cc * 16 + (k & 15);
    int oc  = nt * 16 + (lane & 15);
    float v = (tap < 9) ? w[((size_t)oc * CIN + ci) * 9 + tap] : 0.0f;
    out[e] = (_Float16)v;
}

__global__ void pack_w_kernel(const float* __restrict__ w, _Float16* __restrict__ out,
                              int CIN, int NT, int total)
{
    for (int e = blockIdx.x * 256 + threadIdx.x; e < total; e += gridDim.x * 256)
        pack_one(w, out, CIN, NT, e);
}

__global__ void pack2_kernel(const float* __restrict__ w3, const float* __restrict__ w4,
                             _Float16* __restrict__ o3, _Float16* __restrict__ o4)
{
    int e0 = blockIdx.x * 256 + threadIdx.x;
    if (e0 >= 15360) return;
    if (e0 < 5120) pack_one(w3, o3, 16, 2, e0);
    else           pack_one(w4, o4, 32, 2, e0 - 5120);
}

__global__ void pack6_kernel(const float* __restrict__ w5, const float* __restrict__ w6,
                             const float* __restrict__ w7, const float* __restrict__ w8,
                             const float* __restrict__ w9, const float* __restrict__ w10,
                             _Float16* __restrict__ o5, _Float16* __restrict__ o6,
                             _Float16* __restrict__ o7, _Float16* __restrict__ o8,
                             _Float16* __restrict__ o9, _Float16* __restrict__ o10)
{
    int e = blockIdx.x * 256 + threadIdx.x;
    if (e >= 225280) return;
    if      (e <  15360) pack_one(w5,  o5, 32, 3, e);
    else if (e <  38400) pack_one(w6,  o6, 48, 3, e - 15360);
    else if (e <  69120) pack_one(w7,  o7, 48, 4, e - 38400);
    else if (e < 110080) pack_one(w8,  o8, 64, 4, e - 69120);
    else if (e < 161280) pack_one(w9,  o9, 64, 5, e - 110080);
    else                 pack_one(w10, o10, 80, 5, e - 161280);
}

// ---------------------------------------------------------------------------
// Fused conv1(BN-folded) -> ReLU -> conv2 via MFMA (TH=16). Output NHWC fp16.
// Staging split: wave w handles channel group (w&1)*8..+7 for position half
// (w>>1). 72 weights + 8 biases per wave stay register-resident (~110 VGPR,
// LDS still the occupancy limit). half8 stores at 48B stride = 3x16B odd
// multiple -> conflict-free.
// ---------------------------------------------------------------------------
__global__ __launch_bounds__(256)
void conv12_mfma_kernel(const float* __restrict__ x, _Float16* __restrict__ out,
                        const float* __restrict__ w1f, const float* __restrict__ b1f,
                        const _Float16* __restrict__ w2p,
                        float* __restrict__ bank2, int H, int W)
{
    constexpr int CINP = 24;

    __shared__ float xt[20][36];
    __shared__ __align__(16) _Float16 tile[612 * CINP];
    __shared__ float sred[32];

    const int t = threadIdx.x;
    const int lane = t & 63;
    const int wave = t >> 6;
    const int n = blockIdx.z;

    if (t >= 192 && t < 224) sred[t - 192] = 0.0f;

    const int Y0 = blockIdx.y * 16 - 1;
    const int X0 = blockIdx.x * 32 - 1;

    for (int idx = t; idx < 720; idx += 256) {
        int r = idx / 36, c = idx - r * 36;
        int gy = Y0 - 1 + r, gx = X0 - 1 + c;
        xt[r][c] = ((unsigned)gy < (unsigned)H && (unsigned)gx < (unsigned)W)
                 ? x[((size_t)n * H + gy) * W + gx] : 0.0f;
    }

    // per-wave register-resident weight block: 8 channels
    const int cg8 = wave & 1;
    const int ph  = wave >> 1;
    const int ci0 = cg8 * 8;
    float wr[72], br8[8];
    #pragma unroll
    for (int i = 0; i < 72; i++) wr[i] = w1f[ci0 * 9 + i];
    #pragma unroll
    for (int j = 0; j < 8; j++)  br8[j] = b1f[ci0 + j];
    __syncthreads();

    // conv1 (folded) + ReLU -> fp16 tile; each wave: 306 positions x 8 ch
    const int pend = ph * 306 + 306;
    for (int idx = ph * 306 + lane; idx < pend; idx += 64) {
        int r = idx / 34, c = idx - r * 34;
        int gy = Y0 + r, gx = X0 + c;
        bool vld = (unsigned)gy < (unsigned)H && (unsigned)gx < (unsigned)W;
        float xv[9];
        #pragma unroll
        for (int dy = 0; dy < 3; dy++)
            #pragma unroll
            for (int dx = 0; dx < 3; dx++) xv[dy * 3 + dx] = xt[r + dy][c + dx];
        half8 o;
        #pragma unroll
        for (int j = 0; j < 8; j++) {
            float v = br8[j];
            #pragma unroll
            for (int k = 0; k < 9; k++) v = fmaf(wr[j * 9 + k], xv[k], v);
            o[j] = vld ? (_Float16)fmaxf(v, 0.0f) : (_Float16)0.0f;
        }
        *(half8*)(tile + idx * CINP + ci0) = o;
    }
    __syncthreads();

    floatx4 acc[8];
    #pragma unroll
    for (int i = 0; i < 8; i++) acc[i] = (floatx4){0.f, 0.f, 0.f, 0.f};

    const int m      = lane & 15;
    const int q      = lane >> 4;
    const int ci_off = (q & 1) * 8;

    #pragma unroll
    for (int tp = 0; tp < 5; tp++) {
        half8 bfr = *(const half8*)(w2p + ((size_t)tp << 9) + lane * 8);
        int tap = 2 * tp + (q >> 1);
        if (tap > 8) tap = 8;
        const int dy = tap / 3;
        const int dx = tap - 3 * dy;
        #pragma unroll
        for (int i = 0; i < 8; i++) {
            int mtid = wave * 8 + i;
            int r  = mtid >> 1;
            int c0 = (mtid & 1) * 16;
            int addr = ((r + dy) * 34 + (c0 + m + dx)) * CINP + ci_off;
            half8 a = *(const half8*)(tile + addr);
            acc[i] = __builtin_amdgcn_mfma_f32_16x16x32_f16(a, bfr, acc[i], 0, 0, 0);
        }
    }

    float lsum = 0.0f, lsq = 0.0f;
    #pragma unroll
    for (int i = 0; i < 8; i++) {
        int mtid = wave * 8 + i;
        int r  = mtid >> 1;
        int c0 = (mtid & 1) * 16;
        int oy  = blockIdx.y * 16 + r;
        int oxb = blockIdx.x * 32 + c0 + q * 4;
        if (oy < H) {
            size_t pxb = (size_t)(n * H + oy) * W;
            #pragma unroll
            for (int e = 0; e < 4; e++) {
                int ox = oxb + e;
                if (ox < W) {
                    float rv = roundstore(&out[(pxb + ox) * 16 + m], acc[i][e]);
                    lsum += rv; lsq += rv * rv;
                }
            }
        }
    }
    lsum += __shfl_xor(lsum, 16, 64); lsum += __shfl_xor(lsum, 32, 64);
    lsq  += __shfl_xor(lsq, 16, 64);  lsq  += __shfl_xor(lsq, 32, 64);
    if (q == 0) {
        atomicAdd(&sred[m], lsum);
        atomicAdd(&sred[16 + m], lsq);
    }
    __syncthreads();
    const int bk = (blockIdx.x + blockIdx.y) & 7;
    if (t < 16)       atomicAdd(&bank2[bk * 160 + t], sred[t]);
    else if (t < 32)  atomicAdd(&bank2[bk * 160 + 80 + t - 16], sred[t]);
}

// ---------------------------------------------------------------------------
// MFMA implicit conv, NHWC fp16 (validated round 9). TH=8.
// ---------------------------------------------------------------------------
template<int CIN, int COUT, bool BN_IN, int TH>
__global__ __launch_bounds__(256)
void conv3x3_mfma_kernel(const _Float16* __restrict__ in, _Float16* __restrict__ out,
                         const _Float16* __restrict__ wpack,
                         const float* __restrict__ gb_in,
                         const float* __restrict__ bank_in,
                         float inv_n_in,
                         float* __restrict__ bank_out,
                         int H, int W)
{
    constexpr int CINP = CIN + 8;
    constexpr int CC = CIN / 16;
    constexpr int NT = COUT / 16;
    constexpr int NP = 5;
    constexpr int NI = TH / 2;
    constexpr int PX = (TH + 2) * 34;
    constexpr int CG = CIN / 8;

    __shared__ __align__(16) _Float16 tile[PX * CINP];
    __shared__ float sc[BN_IN ? CIN : 1];
    __shared__ float bi[BN_IN ? CIN : 1];
    __shared__ float sred[2 * COUT];

    const int t = threadIdx.x;
    const int lane = t & 63;
    const int wave = t >> 6;
    const int n = blockIdx.z;

    if (t < 2 * COUT) sred[t] = 0.0f;
    if constexpr (BN_IN) {
        if (t < CIN) {
            float s = 0.0f, sq = 0.0f;
            for (int b = 0; b < 32; b++) {
                s  += bank_in[b * 160 + t];
                sq += bank_in[b * 160 + 80 + t];
            }
            float mu = s * inv_n_in;
            float var = fmaxf(sq * inv_n_in - mu * mu, 0.0f);
            float scale = gb_in[t] * rsqrtf(var + EPS);
            sc[t] = scale;
            bi[t] = gb_in[CIN + t] - mu * scale;
        }
    }
    __syncthreads();

    const int Y0 = blockIdx.y * TH - 1;
    const int X0 = blockIdx.x * 32 - 1;

    for (int v = t; v < PX * CG; v += 256) {
        int p  = v / CG;
        int cg = v - p * CG;
        int tr = p / 34, tc = p - tr * 34;
        int gy = Y0 + tr, gx = X0 + tc;
        half8 v8 = (half8){0, 0, 0, 0, 0, 0, 0, 0};
        if ((unsigned)gy < (unsigned)H && (unsigned)gx < (unsigned)W) {
            v8 = *(const half8*)(in + ((size_t)(n * H + gy) * W + gx) * CIN + cg * 8);
            if constexpr (BN_IN) {
                #pragma unroll
                for (int j = 0; j < 8; j++) {
                    int ci = cg * 8 + j;
                    v8[j] = (_Float16)fmaxf((float)v8[j] * sc[ci] + bi[ci], 0.0f);
                }
            }
        }
        *(half8*)(tile + p * CINP + cg * 8) = v8;
    }
    __syncthreads();

    floatx4 acc[NI][NT];
    #pragma unroll
    for (int i = 0; i < NI; i++)
        #pragma unroll
        for (int nt = 0; nt < NT; nt++) acc[i][nt] = (floatx4){0.f, 0.f, 0.f, 0.f};

    const int m      = lane & 15;
    const int q      = lane >> 4;
    const int ci_off = (q & 1) * 8;

    for (int cc = 0; cc < CC; cc++) {
        #pragma unroll
        for (int tp = 0; tp < NP; tp++) {
            half8 bfr[NT];
            #pragma unroll
            for (int nt = 0; nt < NT; nt++)
                bfr[nt] = *(const half8*)(wpack +
                    (((size_t)(cc * NP + tp) * NT + nt) << 9) + lane * 8);
            int tap = 2 * tp + (q >> 1);
            if (tap > 8) tap = 8;
            const int dy = tap / 3;
            const int dx = tap - 3 * dy;
            #pragma unroll
            for (int i = 0; i < NI; i++) {
                int mtid = wave * NI + i;
                int r  = mtid >> 1;
                int c0 = (mtid & 1) * 16;
                int addr = ((r + dy) * 34 + (c0 + m + dx)) * CINP + cc * 16 + ci_off;
                half8 a = *(const half8*)(tile + addr);
                #pragma unroll
                for (int nt = 0; nt < NT; nt++)
                    acc[i][nt] = __builtin_amdgcn_mfma_f32_16x16x32_f16(
                        a, bfr[nt], acc[i][nt], 0, 0, 0);
            }
        }
    }

    float lsum[NT], lsq[NT];
    #pragma unroll
    for (int nt = 0; nt < NT; nt++) { lsum[nt] = 0.0f; lsq[nt] = 0.0f; }
    #pragma unroll
    for (int i = 0; i < NI; i++) {
        int mtid = wave * NI + i;
        int r  = mtid >> 1;
        int c0 = (mtid & 1) * 16;
        int oy  = blockIdx.y * TH + r;
        int oxb = blockIdx.x * 32 + c0 + q * 4;
        if (oy < H) {
            size_t pxb = (size_t)(n * H + oy) * W;
            #pragma unroll
            for (int e = 0; e < 4; e++) {
                int ox = oxb + e;
                if (ox < W) {
                    #pragma unroll
                    for (int nt = 0; nt < NT; nt++) {
                        float rv = roundstore(&out[(pxb + ox) * COUT + nt * 16 + m],
                                              acc[i][nt][e]);
                        lsum[nt] += rv; lsq[nt] += rv * rv;
                    }
                }
            }
        }
    }
    #pragma unroll
    for (int nt = 0; nt < NT; nt++) {
        float a = lsum[nt], b = lsq[nt];
        a += __shfl_xor(a, 16, 64); a += __shfl_xor(a, 32, 64);
        b += __shfl_xor(b, 16, 64); b += __shfl_xor(b, 32, 64);
        if (q == 0) {
            atomicAdd(&sred[nt * 16 + m], a);
            atomicAdd(&sred[COUT + nt * 16 + m], b);
        }
    }
    __syncthreads();
    const int bk = (blockIdx.x + blockIdx.y) & 31;
    if (t < COUT)           atomicAdd(&bank_out[bk * 160 + t], sred[t]);
    else if (t < 2 * COUT)  atomicAdd(&bank_out[bk * 160 + 80 + t - COUT], sred[t]);
}

// ---------------------------------------------------------------------------
// NHWC 3x3/stride2 VALID maxpool + fused BN-ReLU (validated round 9).
// ---------------------------------------------------------------------------
template<int C>
__global__ __launch_bounds__(256)
void pool_kernel(const _Float16* __restrict__ in, _Float16* __restrict__ out,
                 const float* __restrict__ gb, const float* __restrict__ bank,
                 int nb, float inv_n, int Hin, int Win, int Hout, int Wout)
{
    constexpr int CG = C / 8;
    constexpr int NX = 256 / CG;
    __shared__ float scs[C], bis[C];
    const int t = threadIdx.x;
    if (t < C) {
        float s = 0.0f, sq = 0.0f;
        for (int b = 0; b < nb; b++) {
            s  += bank[b * 160 + t];
            sq += bank[b * 160 + 80 + t];
        }
        float mu = s * inv_n;
        float var = fmaxf(sq * inv_n - mu * mu, 0.0f);
        float scale = gb[t] * rsqrtf(var + EPS);
        scs[t] = scale;
        bis[t] = gb[C + t] - mu * scale;
    }
    __syncthreads();
    const int cg  = t % CG;
    const int oxl = t / CG;
    if (oxl >= NX) return;
    const int ox = blockIdx.x * NX + oxl;
    const int oy = blockIdx.y;
    const int nz = blockIdx.z;
    if (ox >= Wout) return;

    float sc8[8], bi8[8];
    #pragma unroll
    for (int j = 0; j < 8; j++) { sc8[j] = scs[cg * 8 + j]; bi8[j] = bis[cg * 8 + j]; }
    float m[8];
    #pragma unroll
    for (int j = 0; j < 8; j++) m[j] = 0.0f;
    #pragma unroll
    for (int dy = 0; dy < 3; dy++)
        #pragma unroll
        for (int dx = 0; dx < 3; dx++) {
            half8 v = *(const half8*)(in +
                ((size_t)(nz * Hin + 2 * oy + dy) * Win + (2 * ox + dx)) * C + cg * 8);
            #pragma unroll
            for (int j = 0; j < 8; j++)
                m[j] = fmaxf(m[j], fmaxf((float)v[j] * sc8[j] + bi8[j], 0.0f));
        }
    half8 o;
    #pragma unroll
    for (int j = 0; j < 8; j++) o[j] = (_Float16)m[j];
    *(half8*)(out + ((size_t)(nz * Hout + oy) * Wout + ox) * C + cg * 8) = o;
}

// ---------------------------------------------------------------------------
// NHWC tail: per (n, c8-group) block, mean of BN-ReLU over 100x100.
// ---------------------------------------------------------------------------
__global__ __launch_bounds__(256)
void tail_reduce_kernel(const _Float16* __restrict__ in,
                        const float* __restrict__ gb,
                        const float* __restrict__ bank, float inv_n,
                        float* __restrict__ h)
{
    __shared__ float scs[8], bis[8];
    __shared__ float red[4][8];
    const int t  = threadIdx.x;
    const int c8 = blockIdx.x;
    const int nz = blockIdx.y;
    if (t < 8) {
        int c = c8 * 8 + t;
        float s = 0.0f, sq = 0.0f;
        for (int b = 0; b < 32; b++) {
            s  += bank[b * 160 + c];
            sq += bank[b * 160 + 80 + c];
        }
        float mu = s * inv_n;
        float var = fmaxf(sq * inv_n - mu * mu, 0.0f);
        float scale = gb[c] * rsqrtf(var + EPS);
        scs[t] = scale;
        bis[t] = gb[80 + c] - mu * scale;
    }
    __syncthreads();
    float a[8];
    #pragma unroll
    for (int j = 0; j < 8; j++) a[j] = 0.0f;
    for (int px = t; px < 10000; px += 256) {
        half8 v = *(const half8*)(in + ((size_t)nz * 10000 + px) * 80 + c8 * 8);
        #pragma unroll
        for (int j = 0; j < 8; j++)
            a[j] += fmaxf((float)v[j] * scs[j] + bis[j], 0.0f);
    }
    #pragma unroll
    for (int j = 0; j < 8; j++)
        for (int off = 32; off; off >>= 1) a[j] += __shfl_xor(a[j], off, 64);
    if ((t & 63) == 0) {
        #pragma unroll
        for (int j = 0; j < 8; j++) red[t >> 6][j] = a[j];
    }
    __syncthreads();
    if (t < 8)
        h[nz * 80 + c8 * 8 + t] =
            (red[0][t] + red[1][t] + red[2][t] + red[3][t]) * 1e-4f;
}

// BN1d (batch=2, batch stats) + linear [80 -> 40]
__global__ __launch_bounds__(128)
void head_kernel(const float* __restrict__ h, const float* __restrict__ bn_gb,
                 const float* __restrict__ lin_w, const float* __restrict__ lin_b,
                 float* __restrict__ outp)
{
    __shared__ float hn[2][80];
    const int t = threadIdx.x;
    if (t < 80) {
        float a = h[t], b = h[80 + t];
        float mu = 0.5f * (a + b);
        float da = a - mu, db = b - mu;
        float var = 0.5f * (da * da + db * db);
        float inv = rsqrtf(var + EPS);
        float g = bn_gb[t], be = bn_gb[80 + t];
        hn[0][t] = da * inv * g + be;
        hn[1][t] = db * inv * g + be;
    }
    __syncthreads();
    if (t < 80) {
        int n = t / 40, k = t - 40 * (t / 40);
        float o = lin_b[k];
        #pragma unroll 4
        for (int c = 0; c < 80; c++) o += hn[n][c] * lin_w[k * 80 + c];
        outp[n * 40 + k] = o;
    }
}

__global__ void sentinel_kernel(float* outp, float v) {
    if (threadIdx.x < 80) outp[threadIdx.x] = v;
}

extern "C" void kernel_launch(void* const* d_in, const int* in_sizes, int n_in,
                              void* d_out, int out_size, void* d_ws, size_t ws_size,
                              hipStream_t stream) {
    const float* x = (const float*)d_in[0];
    const float* w[10]; const float* gb[10];
    for (int i = 0; i < 10; i++) {
        w[i]  = (const float*)d_in[1 + 2 * i];
        gb[i] = (const float*)d_in[2 + 2 * i];
    }
    const float* bn_gb = (const float*)d_in[21];
    const float* lin_w = (const float*)d_in[22];
    const float* lin_b = (const float*)d_in[23];
    float* outp = (float*)d_out;

    auto ALN = [](size_t v) { return (v + 511) & ~(size_t)511; };

    const size_t E_C2 = (size_t)2 * 16 * 1615 * 1615;
    const size_t E_P1 = (size_t)2 * 16 * 807 * 807;
    const size_t E_C3 = (size_t)2 * 32 * 807 * 807;
    const size_t E_C5 = (size_t)2 * 48 * 403 * 403;
    const size_t E_P3 = (size_t)2 * 48 * 201 * 201;
    const size_t E_C7 = (size_t)2 * 64 * 201 * 201;
    const size_t E_P4 = (size_t)2 * 64 * 100 * 100;
    const size_t E_C9 = (size_t)2 * 80 * 100 * 100;

    const size_t STATS = 8192;
    const size_t R0    = ALN(E_C2 * 2);
    const size_t BASE_END = STATS + R0 + ALN(E_P1 * 2);      // 208,615,424
    const size_t NB2_BYTES = 8 * 160 * sizeof(float);
    const size_t NEED  = BASE_END + NB2_BYTES;               // <= proven 208,623,104

    if (ws_size < NEED) {
        sentinel_kernel<<<1, 128, 0, stream>>>(outp, (float)(ws_size >> 20) * 1000.0f);
        return;
    }

    char* base = (char*)d_ws + STATS;
    float* stats = (float*)d_ws;
    float* w1f   = stats + 320;
    float* b1f   = stats + 470;
    float* hbuf  = stats + 1600;

    const size_t Z_C3 = ALN(E_C3 * 2);
    const size_t Z_C5 = ALN(E_C5 * 2);
    const size_t Z_C7 = ALN(E_C7 * 2);
    const size_t Z_P4 = ALN(E_P4 * 2);
    const size_t Z_C9 = ALN(E_C9 * 2);

    _Float16* C2  = (_Float16*)base;
    _Float16* P1  = (_Float16*)(base + R0);
    _Float16* C3  = (_Float16*)base;
    _Float16* C4  = (_Float16*)(base + Z_C3);
    _Float16* P2  = (_Float16*)(base + R0);
    _Float16* C5  = (_Float16*)base;
    _Float16* C6  = (_Float16*)(base + Z_C5);
    _Float16* P3  = (_Float16*)(base + 2 * Z_C5);
    _Float16* C7  = (_Float16*)base;
    _Float16* C8  = (_Float16*)(base + Z_C7);
    _Float16* P4  = (_Float16*)(base + 2 * Z_C7);
    _Float16* C9  = (_Float16*)(base + 2 * Z_C7 + Z_P4);
    _Float16* C10 = (_Float16*)(base + 2 * Z_C7 + Z_P4 + Z_C9);

    const size_t G1 = Z_C3 * 2;
    const size_t G2 = ALN(ALN(E_C5 * 4) * 2 + ALN(E_P3 * 4));
    _Float16* w2p  = (_Float16*)(base + R0);
    _Float16* w3p  = (_Float16*)(base + G1);
    _Float16* w4p  = (_Float16*)(base + G1 + 10240);
    _Float16* w5p  = (_Float16*)(base + G2);
    _Float16* w6p  = (_Float16*)(base + G2 + 30720);
    _Float16* w7p  = (_Float16*)(base + G2 + 76800);
    _Float16* w8p  = (_Float16*)(base + G2 + 138240);
    _Float16* w9p  = (_Float16*)(base + G2 + 220160);
    _Float16* w10p = (_Float16*)(base + G2 + 322560);

    float* B2  = (float*)((char*)d_ws + BASE_END);
    float* BK3 = (float*)(base + G1 + 32768);
    auto SL = [&](int layer) { return BK3 + (size_t)(layer - 3) * 32 * 160; };

    hipMemsetAsync(d_ws, 0, STATS, stream);
    hipMemsetAsync(B2, 0, NB2_BYTES, stream);

    const float i1615 = 1.0f / 5216450.0f;
    const float i807  = 1.0f / 1302498.0f;
    const float i403  = 1.0f / 324818.0f;
    const float i201  = 1.0f / 80802.0f;
    const float i100  = 1.0f / 20000.0f;
    dim3 blk(256);
    float* st = stats;

    // Block 0 @ 1615
    conv1_stats_kernel<<<dim3(51, 13, 2), blk, 0, stream>>>(
        x, w[0], st, 1615, 1615);
    pack_w_kernel<<<dim3(10), blk, 0, stream>>>(w[1], w2p, 16, 1, 1 * 5 * 1 * 512);
    fold_w1_kernel<<<dim3(1), dim3(160), 0, stream>>>(
        w[0], gb[0], st, i1615, w1f, b1f);
    conv12_mfma_kernel<<<dim3(51, 101, 2), blk, 0, stream>>>(
        x, C2, w1f, b1f, w2p, B2, 1615, 1615);
    pool_kernel<16><<<dim3(7, 807, 2), blk, 0, stream>>>(
        C2, P1, gb[1], B2, 8, i1615, 1615, 1615, 807, 807);

    // C2 dead: zero layer-3..10 banks, pack w3/w4 (merged)
    hipMemsetAsync(BK3, 0, 8 * 32 * 160 * sizeof(float), stream);
    pack2_kernel<<<dim3(60), blk, 0, stream>>>(w[2], w[3], w3p, w4p);

    // Block 1 @ 807 (MFMA, TH=8)
    conv3x3_mfma_kernel<16, 32, false, 8><<<dim3(26, 101, 2), blk, 0, stream>>>(
        P1, C3, w3p, nullptr, nullptr, 0.f, SL(3), 807, 807);
    conv3x3_mfma_kernel<32, 32, true, 8><<<dim3(26, 101, 2), blk, 0, stream>>>(
        C3, C4, w4p, gb[2], SL(3), i807, SL(4), 807, 807);
    pool_kernel<32><<<dim3(7, 403, 2), blk, 0, stream>>>(
        C4, P2, gb[3], SL(4), 32, i807, 807, 807, 403, 403);

    // pack w5..w10 (merged)
    pack6_kernel<<<dim3(880), blk, 0, stream>>>(
        w[4], w[5], w[6], w[7], w[8], w[9],
        w5p, w6p, w7p, w8p, w9p, w10p);

    // Block 2 @ 403
    conv3x3_mfma_kernel<32, 48, false, 8><<<dim3(13, 51, 2), blk, 0, stream>>>(
        P2, C5, w5p, nullptr, nullptr, 0.f, SL(5), 403, 403);
    conv3x3_mfma_kernel<48, 48, true, 8><<<dim3(13, 51, 2), blk, 0, stream>>>(
        C5, C6, w6p, gb[4], SL(5), i403, SL(6), 403, 403);
    pool_kernel<48><<<dim3(5, 201, 2), blk, 0, stream>>>(
        C6, P3, gb[5], SL(6), 32, i403, 403, 403, 201, 201);

    // Block 3 @ 201
    conv3x3_mfma_kernel<48, 64, false, 8><<<dim3(7, 26, 2), blk, 0, stream>>>(
        P3, C7, w7p, nullptr, nullptr, 0.f, SL(7), 201, 201);
    conv3x3_mfma_kernel<64, 64, true, 8><<<dim3(7, 26, 2), blk, 0, stream>>>(
        C7, C8, w8p, gb[6], SL(7), i201, SL(8), 201, 201);
    pool_kernel<64><<<dim3(4, 100, 2), blk, 0, stream>>>(
        C8, P4, gb[7], SL(8), 32, i201, 201, 201, 100, 100);

    // Block 4 @ 100
    conv3x3_mfma_kernel<64, 80, false, 8><<<dim3(4, 13, 2), blk, 0, stream>>>(
        P4, C9, w9p, nullptr, nullptr, 0.f, SL(9), 100, 100);
    conv3x3_mfma_kernel<80, 80, true, 8><<<dim3(4, 13, 2), blk, 0, stream>>>(
        C9, C10, w10p, gb[8], SL(9), i100, SL(10), 100, 100);

    // Tail
    tail_reduce_kernel<<<dim3(10, 2), blk, 0, stream>>>(
        C10, gb[9], SL(10), i100, hbuf);
    head_kernel<<<dim3(1), dim3(128), 0, stream>>>(
        hbuf, bn_gb, lin_w, lin_b, outp);

    (void)in_sizes; (void)n_in; (void)out_size; (void)ws_size;
}

// Round 14
// 604.148 us; speedup vs baseline: 1.0587x; 1.0587x over previous
//
#include <hip/hip_runtime.h>
#include <hip/hip_fp16.h>

typedef _Float16 half8 __attribute__((ext_vector_type(8)));
typedef _Float16 half4 __attribute__((ext_vector_type(4)));
typedef float floatx4 __attribute__((ext_vector_type(4)));

#define EPS 1e-5f

__device__ inline float roundstore(_Float16* p, float v){
    _Float16 h = (_Float16)v; *p = h; return (float)h; }

// ---------------------------------------------------------------------------
// conv1 stats: conv1 (1->16ch) from x (NCHW fp32), per-channel sum/sumsq.
// ---------------------------------------------------------------------------
__global__ __launch_bounds__(256)
void conv1_stats_kernel(const float* __restrict__ x, const float* __restrict__ w1,
                        float* __restrict__ stats_out, int H, int W)
{
    __shared__ float xt[10][34];
    __shared__ float wred[4][32];
    const int t = threadIdx.x;
    const int n = blockIdx.z;
    const int tx = t & 31, ty = t >> 5;
    const int ox = blockIdx.x * 32 + tx;
    const int x0 = blockIdx.x * 32 - 1;

    float racc[16], rqacc[16];
    #pragma unroll
    for (int oc = 0; oc < 16; oc++) { racc[oc] = 0.0f; rqacc[oc] = 0.0f; }

    for (int yt = 0; yt < 16; yt++) {
        const int ybase = (blockIdx.y * 16 + yt) * 8;
        const int oy = ybase + ty;
        const int y0 = ybase - 1;
        __syncthreads();
        for (int idx = t; idx < 340; idx += 256) {
            int r = idx / 34, c = idx - r * 34;
            int gy = y0 + r, gx = x0 + c;
            xt[r][c] = ((unsigned)gy < (unsigned)H && (unsigned)gx < (unsigned)W)
                     ? x[((size_t)n * H + gy) * W + gx] : 0.0f;
        }
        __syncthreads();
        if (oy < H && ox < W) {
            float win[9];
            #pragma unroll
            for (int dy = 0; dy < 3; dy++)
                #pragma unroll
                for (int dx = 0; dx < 3; dx++) win[dy * 3 + dx] = xt[ty + dy][tx + dx];
            #pragma unroll
            for (int oc = 0; oc < 16; oc++) {
                float v = 0.0f;
                #pragma unroll
                for (int k = 0; k < 9; k++) v = fmaf(w1[oc * 9 + k], win[k], v);
                racc[oc] += v; rqacc[oc] += v * v;
            }
        }
    }

    #pragma unroll
    for (int oc = 0; oc < 16; oc++) {
        float a = racc[oc], b = rqacc[oc];
        for (int off = 32; off; off >>= 1) {
            a += __shfl_xor(a, off, 64);
            b += __shfl_xor(b, off, 64);
        }
        racc[oc] = a; rqacc[oc] = b;
    }
    const int wave = t >> 6;
    if ((t & 63) == 0) {
        #pragma unroll
        for (int oc = 0; oc < 16; oc++) {
            wred[wave][oc] = racc[oc];
            wred[wave][16 + oc] = rqacc[oc];
        }
    }
    __syncthreads();
    if (t < 32) {
        float v = wred[0][t] + wred[1][t] + wred[2][t] + wred[3][t];
        atomicAdd(&stats_out[(t < 16 ? 0 : 80) + (t & 15)], v);
    }
}

// ---------------------------------------------------------------------------
// Fold BN1 into conv1 weights: w1f = sc1*w1, b1f = bi1. One block.
// ---------------------------------------------------------------------------
__global__ void fold_w1_kernel(const float* __restrict__ w1, const float* __restrict__ gb1,
                               const float* __restrict__ stats1, float inv_n,
                               float* __restrict__ w1f, float* __restrict__ b1f)
{
    __shared__ float sc[16], bi[16];
    const int t = threadIdx.x;
    if (t < 16) {
        float s = stats1[t], sq = stats1[80 + t];
        float mu = s * inv_n;
        float var = fmaxf(sq * inv_n - mu * mu, 0.0f);
        float scl = gb1[t] * rsqrtf(var + EPS);
        sc[t] = scl;
        bi[t] = gb1[16 + t] - mu * scl;
    }
    __syncthreads();
    if (t < 144) w1f[t] = w1[t] * sc[t / 9];
    if (t < 16)  b1f[t] = bi[t];
}

// ---------------------------------------------------------------------------
// Weight pre-pack into exact MFMA B-fragment lane order (validated).
// ---------------------------------------------------------------------------
__device__ inline void pack_one(const float* __restrict__ w, _Float16* __restrict__ out,
                                int CIN, int NT, int e)
{
    int j    = e & 7;
    int lane = (e >> 3) & 63;
    int frag = e >> 9;
    int nt = frag % NT;
    int tp = (frag / NT) % 5;
    int cc = frag / (NT * 5);
    int k   = ((lane >> 4) << 3) + j;
    int tap = 2 * tp + (k >> 4);
    int ci  = cc * 16 + (k & 15);
    int oc  = nt * 16 + (lane & 15);
    float v = (tap < 9) ? w[((size_t)oc * CIN + ci) * 9 + tap] : 0.0f;
    out[e] = (_Float16)v;
}

__global__ void pack_w_kernel(const float* __restrict__ w, _Float16* __restrict__ out,
                              int CIN, int NT, int total)
{
    for (int e = blockIdx.x * 256 + threadIdx.x; e < total; e += gridDim.x * 256)
        pack_one(w, out, CIN, NT, e);
}

__global__ void pack2_kernel(const float* __restrict__ w3, const float* __restrict__ w4,
                             _Float16* __restrict__ o3, _Float16* __restrict__ o4)
{
    int e0 = blockIdx.x * 256 + threadIdx.x;
    if (e0 >= 15360) return;
    if (e0 < 5120) pack_one(w3, o3, 16, 2, e0);
    else           pack_one(w4, o4, 32, 2, e0 - 5120);
}

__global__ void pack6_kernel(const float* __restrict__ w5, const float* __restrict__ w6,
                             const float* __restrict__ w7, const float* __restrict__ w8,
                             const float* __restrict__ w9, const float* __restrict__ w10,
                             _Float16* __restrict__ o5, _Float16* __restrict__ o6,
                             _Float16* __restrict__ o7, _Float16* __restrict__ o8,
                             _Float16* __restrict__ o9, _Float16* __restrict__ o10)
{
    int e = blockIdx.x * 256 + threadIdx.x;
    if (e >= 225280) return;
    if      (e <  15360) pack_one(w5,  o5, 32, 3, e);
    else if (e <  38400) pack_one(w6,  o6, 48, 3, e - 15360);
    else if (e <  69120) pack_one(w7,  o7, 48, 4, e - 38400);
    else if (e < 110080) pack_one(w8,  o8, 64, 4, e - 69120);
    else if (e < 161280) pack_one(w9,  o9, 64, 5, e - 110080);
    else                 pack_one(w10, o10, 80, 5, e - 161280);
}

// ---------------------------------------------------------------------------
// Fused conv1(BN-folded) -> ReLU -> conv2 via MFMA (TH=16). Output NHWC fp16.
// Staging (round-12 proven best): wave w computes channels 4w..4w+3 for all
// positions; its 36 weights + 4 biases load once via wave-uniform addresses
// (scalar loads -> SGPRs).
// ---------------------------------------------------------------------------
__global__ __launch_bounds__(256)
void conv12_mfma_kernel(const float* __restrict__ x, _Float16* __restrict__ out,
                        const float* __restrict__ w1f, const float* __restrict__ b1f,
                        const _Float16* __restrict__ w2p,
                        float* __restrict__ bank2, int H, int W)
{
    constexpr int CINP = 24;

    __shared__ float xt[20][36];
    __shared__ __align__(16) _Float16 tile[612 * CINP];
    __shared__ float sred[32];

    const int t = threadIdx.x;
    const int lane = t & 63;
    const int wave = t >> 6;
    const int n = blockIdx.z;

    if (t >= 192 && t < 224) sred[t - 192] = 0.0f;

    const int Y0 = blockIdx.y * 16 - 1;
    const int X0 = blockIdx.x * 32 - 1;

    for (int idx = t; idx < 720; idx += 256) {
        int r = idx / 36, c = idx - r * 36;
        int gy = Y0 - 1 + r, gx = X0 - 1 + c;
        xt[r][c] = ((unsigned)gy < (unsigned)H && (unsigned)gx < (unsigned)W)
                 ? x[((size_t)n * H + gy) * W + gx] : 0.0f;
    }

    // wave-uniform weight block: channels ci0..ci0+3 (scalar loads)
    const int ci0 = wave * 4;
    float wr[36], br4[4];
    #pragma unroll
    for (int i = 0; i < 36; i++) wr[i] = w1f[ci0 * 9 + i];
    #pragma unroll
    for (int j = 0; j < 4; j++)  br4[j] = b1f[ci0 + j];
    __syncthreads();

    for (int idx = lane; idx < 612; idx += 64) {
        int r = idx / 34, c = idx - r * 34;
        int gy = Y0 + r, gx = X0 + c;
        bool vld = (unsigned)gy < (unsigned)H && (unsigned)gx < (unsigned)W;
        float xv[9];
        #pragma unroll
        for (int dy = 0; dy < 3; dy++)
            #pragma unroll
            for (int dx = 0; dx < 3; dx++) xv[dy * 3 + dx] = xt[r + dy][c + dx];
        half4 o;
        #pragma unroll
        for (int j = 0; j < 4; j++) {
            float v = br4[j];
            #pragma unroll
            for (int k = 0; k < 9; k++) v = fmaf(wr[j * 9 + k], xv[k], v);
            o[j] = vld ? (_Float16)fmaxf(v, 0.0f) : (_Float16)0.0f;
        }
        *(half4*)(tile + idx * CINP + ci0) = o;
    }
    __syncthreads();

    floatx4 acc[8];
    #pragma unroll
    for (int i = 0; i < 8; i++) acc[i] = (floatx4){0.f, 0.f, 0.f, 0.f};

    const int m      = lane & 15;
    const int q      = lane >> 4;
    const int ci_off = (q & 1) * 8;

    #pragma unroll
    for (int tp = 0; tp < 5; tp++) {
        half8 bfr = *(const half8*)(w2p + ((size_t)tp << 9) + lane * 8);
        int tap = 2 * tp + (q >> 1);
        if (tap > 8) tap = 8;
        const int dy = tap / 3;
        const int dx = tap - 3 * dy;
        #pragma unroll
        for (int i = 0; i < 8; i++) {
            int mtid = wave * 8 + i;
            int r  = mtid >> 1;
            int c0 = (mtid & 1) * 16;
            int addr = ((r + dy) * 34 + (c0 + m + dx)) * CINP + ci_off;
            half8 a = *(const half8*)(tile + addr);
            acc[i] = __builtin_amdgcn_mfma_f32_16x16x32_f16(a, bfr, acc[i], 0, 0, 0);
        }
    }

    float lsum = 0.0f, lsq = 0.0f;
    #pragma unroll
    for (int i = 0; i < 8; i++) {
        int mtid = wave * 8 + i;
        int r  = mtid >> 1;
        int c0 = (mtid & 1) * 16;
        int oy  = blockIdx.y * 16 + r;
        int oxb = blockIdx.x * 32 + c0 + q * 4;
        if (oy < H) {
            size_t pxb = (size_t)(n * H + oy) * W;
            #pragma unroll
            for (int e = 0; e < 4; e++) {
                int ox = oxb + e;
                if (ox < W) {
                    float rv = roundstore(&out[(pxb + ox) * 16 + m], acc[i][e]);
                    lsum += rv; lsq += rv * rv;
                }
            }
        }
    }
    lsum += __shfl_xor(lsum, 16, 64); lsum += __shfl_xor(lsum, 32, 64);
    lsq  += __shfl_xor(lsq, 16, 64);  lsq  += __shfl_xor(lsq, 32, 64);
    if (q == 0) {
        atomicAdd(&sred[m], lsum);
        atomicAdd(&sred[16 + m], lsq);
    }
    __syncthreads();
    const int bk = (blockIdx.x + blockIdx.y) & 7;
    if (t < 16)       atomicAdd(&bank2[bk * 160 + t], sred[t]);
    else if (t < 32)  atomicAdd(&bank2[bk * 160 + 80 + t - 16], sred[t]);
}

// ---------------------------------------------------------------------------
// MFMA implicit conv, NHWC fp16 (validated round 9). TH = tile height.
// ---------------------------------------------------------------------------
template<int CIN, int COUT, bool BN_IN, int TH>
__global__ __launch_bounds__(256)
void conv3x3_mfma_kernel(const _Float16* __restrict__ in, _Float16* __restrict__ out,
                         const _Float16* __restrict__ wpack,
                         const float* __restrict__ gb_in,
                         const float* __restrict__ bank_in,
                         float inv_n_in,
                         float* __restrict__ bank_out,
                         int H, int W)
{
    constexpr int CINP = CIN + 8;
    constexpr int CC = CIN / 16;
    constexpr int NT = COUT / 16;
    constexpr int NP = 5;
    constexpr int NI = TH / 2;
    constexpr int PX = (TH + 2) * 34;
    constexpr int CG = CIN / 8;

    __shared__ __align__(16) _Float16 tile[PX * CINP];
    __shared__ float sc[BN_IN ? CIN : 1];
    __shared__ float bi[BN_IN ? CIN : 1];
    __shared__ float sred[2 * COUT];

    const int t = threadIdx.x;
    const int lane = t & 63;
    const int wave = t >> 6;
    const int n = blockIdx.z;

    if (t < 2 * COUT) sred[t] = 0.0f;
    if constexpr (BN_IN) {
        if (t < CIN) {
            float s = 0.0f, sq = 0.0f;
            for (int b = 0; b < 32; b++) {
                s  += bank_in[b * 160 + t];
                sq += bank_in[b * 160 + 80 + t];
            }
            float mu = s * inv_n_in;
            float var = fmaxf(sq * inv_n_in - mu * mu, 0.0f);
            float scale = gb_in[t] * rsqrtf(var + EPS);
            sc[t] = scale;
            bi[t] = gb_in[CIN + t] - mu * scale;
        }
    }
    __syncthreads();

    const int Y0 = blockIdx.y * TH - 1;
    const int X0 = blockIdx.x * 32 - 1;

    for (int v = t; v < PX * CG; v += 256) {
        int p  = v / CG;
        int cg = v - p * CG;
        int tr = p / 34, tc = p - tr * 34;
        int gy = Y0 + tr, gx = X0 + tc;
        half8 v8 = (half8){0, 0, 0, 0, 0, 0, 0, 0};
        if ((unsigned)gy < (unsigned)H && (unsigned)gx < (unsigned)W) {
            v8 = *(const half8*)(in + ((size_t)(n * H + gy) * W + gx) * CIN + cg * 8);
            if constexpr (BN_IN) {
                #pragma unroll
                for (int j = 0; j < 8; j++) {
                    int ci = cg * 8 + j;
                    v8[j] = (_Float16)fmaxf((float)v8[j] * sc[ci] + bi[ci], 0.0f);
                }
            }
        }
        *(half8*)(tile + p * CINP + cg * 8) = v8;
    }
    __syncthreads();

    floatx4 acc[NI][NT];
    #pragma unroll
    for (int i = 0; i < NI; i++)
        #pragma unroll
        for (int nt = 0; nt < NT; nt++) acc[i][nt] = (floatx4){0.f, 0.f, 0.f, 0.f};

    const int m      = lane & 15;
    const int q      = lane >> 4;
    const int ci_off = (q & 1) * 8;

    for (int cc = 0; cc < CC; cc++) {
        #pragma unroll
        for (int tp = 0; tp < NP; tp++) {
            half8 bfr[NT];
            #pragma unroll
            for (int nt = 0; nt < NT; nt++)
                bfr[nt] = *(const half8*)(wpack +
                    (((size_t)(cc * NP + tp) * NT + nt) << 9) + lane * 8);
            int tap = 2 * tp + (q >> 1);
            if (tap > 8) tap = 8;
            const int dy = tap / 3;
            const int dx = tap - 3 * dy;
            #pragma unroll
            for (int i = 0; i < NI; i++) {
                int mtid = wave * NI + i;
                int r  = mtid >> 1;
                int c0 = (mtid & 1) * 16;
                int addr = ((r + dy) * 34 + (c0 + m + dx)) * CINP + cc * 16 + ci_off;
                half8 a = *(const half8*)(tile + addr);
                #pragma unroll
                for (int nt = 0; nt < NT; nt++)
                    acc[i][nt] = __builtin_amdgcn_mfma_f32_16x16x32_f16(
                        a, bfr[nt], acc[i][nt], 0, 0, 0);
            }
        }
    }

    float lsum[NT], lsq[NT];
    #pragma unroll
    for (int nt = 0; nt < NT; nt++) { lsum[nt] = 0.0f; lsq[nt] = 0.0f; }
    #pragma unroll
    for (int i = 0; i < NI; i++) {
        int mtid = wave * NI + i;
        int r  = mtid >> 1;
        int c0 = (mtid & 1) * 16;
        int oy  = blockIdx.y * TH + r;
        int oxb = blockIdx.x * 32 + c0 + q * 4;
        if (oy < H) {
            size_t pxb = (size_t)(n * H + oy) * W;
            #pragma unroll
            for (int e = 0; e < 4; e++) {
                int ox = oxb + e;
                if (ox < W) {
                    #pragma unroll
                    for (int nt = 0; nt < NT; nt++) {
                        float rv = roundstore(&out[(pxb + ox) * COUT + nt * 16 + m],
                                              acc[i][nt][e]);
                        lsum[nt] += rv; lsq[nt] += rv * rv;
                    }
                }
            }
        }
    }
    #pragma unroll
    for (int nt = 0; nt < NT; nt++) {
        float a = lsum[nt], b = lsq[nt];
        a += __shfl_xor(a, 16, 64); a += __shfl_xor(a, 32, 64);
        b += __shfl_xor(b, 16, 64); b += __shfl_xor(b, 32, 64);
        if (q == 0) {
            atomicAdd(&sred[nt * 16 + m], a);
            atomicAdd(&sred[COUT + nt * 16 + m], b);
        }
    }
    __syncthreads();
    const int bk = (blockIdx.x + blockIdx.y) & 31;
    if (t < COUT)           atomicAdd(&bank_out[bk * 160 + t], sred[t]);
    else if (t < 2 * COUT)  atomicAdd(&bank_out[bk * 160 + 80 + t - COUT], sred[t]);
}

// ---------------------------------------------------------------------------
// NHWC 3x3/stride2 VALID maxpool + fused BN-ReLU (validated round 9).
// ---------------------------------------------------------------------------
template<int C>
__global__ __launch_bounds__(256)
void pool_kernel(const _Float16* __restrict__ in, _Float16* __restrict__ out,
                 const float* __restrict__ gb, const float* __restrict__ bank,
                 int nb, float inv_n, int Hin, int Win, int Hout, int Wout)
{
    constexpr int CG = C / 8;
    constexpr int NX = 256 / CG;
    __shared__ float scs[C], bis[C];
    const int t = threadIdx.x;
    if (t < C) {
        float s = 0.0f, sq = 0.0f;
        for (int b = 0; b < nb; b++) {
            s  += bank[b * 160 + t];
            sq += bank[b * 160 + 80 + t];
        }
        float mu = s * inv_n;
        float var = fmaxf(sq * inv_n - mu * mu, 0.0f);
        float scale = gb[t] * rsqrtf(var + EPS);
        scs[t] = scale;
        bis[t] = gb[C + t] - mu * scale;
    }
    __syncthreads();
    const int cg  = t % CG;
    const int oxl = t / CG;
    if (oxl >= NX) return;
    const int ox = blockIdx.x * NX + oxl;
    const int oy = blockIdx.y;
    const int nz = blockIdx.z;
    if (ox >= Wout) return;

    float sc8[8], bi8[8];
    #pragma unroll
    for (int j = 0; j < 8; j++) { sc8[j] = scs[cg * 8 + j]; bi8[j] = bis[cg * 8 + j]; }
    float m[8];
    #pragma unroll
    for (int j = 0; j < 8; j++) m[j] = 0.0f;
    #pragma unroll
    for (int dy = 0; dy < 3; dy++)
        #pragma unroll
        for (int dx = 0; dx < 3; dx++) {
            half8 v = *(const half8*)(in +
                ((size_t)(nz * Hin + 2 * oy + dy) * Win + (2 * ox + dx)) * C + cg * 8);
            #pragma unroll
            for (int j = 0; j < 8; j++)
                m[j] = fmaxf(m[j], fmaxf((float)v[j] * sc8[j] + bi8[j], 0.0f));
        }
    half8 o;
    #pragma unroll
    for (int j = 0; j < 8; j++) o[j] = (_Float16)m[j];
    *(half8*)(out + ((size_t)(nz * Hout + oy) * Wout + ox) * C + cg * 8) = o;
}

// ---------------------------------------------------------------------------
// NHWC tail: per (n, c8-group) block, mean of BN-ReLU over 100x100.
// ---------------------------------------------------------------------------
__global__ __launch_bounds__(256)
void tail_reduce_kernel(const _Float16* __restrict__ in,
                        const float* __restrict__ gb,
                        const float* __restrict__ bank, float inv_n,
                        float* __restrict__ h)
{
    __shared__ float scs[8], bis[8];
    __shared__ float red[4][8];
    const int t  = threadIdx.x;
    const int c8 = blockIdx.x;
    const int nz = blockIdx.y;
    if (t < 8) {
        int c = c8 * 8 + t;
        float s = 0.0f, sq = 0.0f;
        for (int b = 0; b < 32; b++) {
            s  += bank[b * 160 + c];
            sq += bank[b * 160 + 80 + c];
        }
        float mu = s * inv_n;
        float var = fmaxf(sq * inv_n - mu * mu, 0.0f);
        float scale = gb[c] * rsqrtf(var + EPS);
        scs[t] = scale;
        bis[t] = gb[80 + c] - mu * scale;
    }
    __syncthreads();
    float a[8];
    #pragma unroll
    for (int j = 0; j < 8; j++) a[j] = 0.0f;
    for (int px = t; px < 10000; px += 256) {
        half8 v = *(const half8*)(in + ((size_t)nz * 10000 + px) * 80 + c8 * 8);
        #pragma unroll
        for (int j = 0; j < 8; j++)
            a[j] += fmaxf((float)v[j] * scs[j] + bis[j], 0.0f);
    }
    #pragma unroll
    for (int j = 0; j < 8; j++)
        for (int off = 32; off; off >>= 1) a[j] += __shfl_xor(a[j], off, 64);
    if ((t & 63) == 0) {
        #pragma unroll
        for (int j = 0; j < 8; j++) red[t >> 6][j] = a[j];
    }
    __syncthreads();
    if (t < 8)
        h[nz * 80 + c8 * 8 + t] =
            (red[0][t] + red[1][t] + red[2][t] + red[3][t]) * 1e-4f;
}

// BN1d (batch=2, batch stats) + linear [80 -> 40]
__global__ __launch_bounds__(128)
void head_kernel(const float* __restrict__ h, const float* __restrict__ bn_gb,
                 const float* __restrict__ lin_w, const float* __restrict__ lin_b,
                 float* __restrict__ outp)
{
    __shared__ float hn[2][80];
    const int t = threadIdx.x;
    if (t < 80) {
        float a = h[t], b = h[80 + t];
        float mu = 0.5f * (a + b);
        float da = a - mu, db = b - mu;
        float var = 0.5f * (da * da + db * db);
        float inv = rsqrtf(var + EPS);
        float g = bn_gb[t], be = bn_gb[80 + t];
        hn[0][t] = da * inv * g + be;
        hn[1][t] = db * inv * g + be;
    }
    __syncthreads();
    if (t < 80) {
        int n = t / 40, k = t - 40 * (t / 40);
        float o = lin_b[k];
        #pragma unroll 4
        for (int c = 0; c < 80; c++) o += hn[n][c] * lin_w[k * 80 + c];
        outp[n * 40 + k] = o;
    }
}

__global__ void sentinel_kernel(float* outp, float v) {
    if (threadIdx.x < 80) outp[threadIdx.x] = v;
}

extern "C" void kernel_launch(void* const* d_in, const int* in_sizes, int n_in,
                              void* d_out, int out_size, void* d_ws, size_t ws_size,
                              hipStream_t stream) {
    const float* x = (const float*)d_in[0];
    const float* w[10]; const float* gb[10];
    for (int i = 0; i < 10; i++) {
        w[i]  = (const float*)d_in[1 + 2 * i];
        gb[i] = (const float*)d_in[2 + 2 * i];
    }
    const float* bn_gb = (const float*)d_in[21];
    const float* lin_w = (const float*)d_in[22];
    const float* lin_b = (const float*)d_in[23];
    float* outp = (float*)d_out;

    auto ALN = [](size_t v) { return (v + 511) & ~(size_t)511; };

    const size_t E_C2 = (size_t)2 * 16 * 1615 * 1615;
    const size_t E_P1 = (size_t)2 * 16 * 807 * 807;
    const size_t E_C3 = (size_t)2 * 32 * 807 * 807;
    const size_t E_C5 = (size_t)2 * 48 * 403 * 403;
    const size_t E_P3 = (size_t)2 * 48 * 201 * 201;
    const size_t E_C7 = (size_t)2 * 64 * 201 * 201;
    const size_t E_P4 = (size_t)2 * 64 * 100 * 100;
    const size_t E_C9 = (size_t)2 * 80 * 100 * 100;

    const size_t STATS = 8192;
    const size_t R0    = ALN(E_C2 * 2);
    const size_t BASE_END = STATS + R0 + ALN(E_P1 * 2);      // 208,615,424
    const size_t NB2_BYTES = 8 * 160 * sizeof(float);
    const size_t NEED  = BASE_END + NB2_BYTES;               // <= proven 208,623,104

    if (ws_size < NEED) {
        sentinel_kernel<<<1, 128, 0, stream>>>(outp, (float)(ws_size >> 20) * 1000.0f);
        return;
    }

    char* base = (char*)d_ws + STATS;
    float* stats = (float*)d_ws;
    float* w1f   = stats + 320;
    float* b1f   = stats + 470;
    float* hbuf  = stats + 1600;

    const size_t Z_C3 = ALN(E_C3 * 2);
    const size_t Z_C5 = ALN(E_C5 * 2);
    const size_t Z_C7 = ALN(E_C7 * 2);
    const size_t Z_P4 = ALN(E_P4 * 2);
    const size_t Z_C9 = ALN(E_C9 * 2);

    _Float16* C2  = (_Float16*)base;
    _Float16* P1  = (_Float16*)(base + R0);
    _Float16* C3  = (_Float16*)base;
    _Float16* C4  = (_Float16*)(base + Z_C3);
    _Float16* P2  = (_Float16*)(base + R0);
    _Float16* C5  = (_Float16*)base;
    _Float16* C6  = (_Float16*)(base + Z_C5);
    _Float16* P3  = (_Float16*)(base + 2 * Z_C5);
    _Float16* C7  = (_Float16*)base;
    _Float16* C8  = (_Float16*)(base + Z_C7);
    _Float16* P4  = (_Float16*)(base + 2 * Z_C7);
    _Float16* C9  = (_Float16*)(base + 2 * Z_C7 + Z_P4);
    _Float16* C10 = (_Float16*)(base + 2 * Z_C7 + Z_P4 + Z_C9);

    const size_t G1 = Z_C3 * 2;
    const size_t G2 = ALN(ALN(E_C5 * 4) * 2 + ALN(E_P3 * 4));
    _Float16* w2p  = (_Float16*)(base + R0);
    _Float16* w3p  = (_Float16*)(base + G1);
    _Float16* w4p  = (_Float16*)(base + G1 + 10240);
    _Float16* w5p  = (_Float16*)(base + G2);
    _Float16* w6p  = (_Float16*)(base + G2 + 30720);
    _Float16* w7p  = (_Float16*)(base + G2 + 76800);
    _Float16* w8p  = (_Float16*)(base + G2 + 138240);
    _Float16* w9p  = (_Float16*)(base + G2 + 220160);
    _Float16* w10p = (_Float16*)(base + G2 + 322560);

    float* B2  = (float*)((char*)d_ws + BASE_END);
    float* BK3 = (float*)(base + G1 + 32768);
    auto SL = [&](int layer) { return BK3 + (size_t)(layer - 3) * 32 * 160; };

    hipMemsetAsync(d_ws, 0, STATS, stream);
    hipMemsetAsync(B2, 0, NB2_BYTES, stream);

    const float i1615 = 1.0f / 5216450.0f;
    const float i807  = 1.0f / 1302498.0f;
    const float i403  = 1.0f / 324818.0f;
    const float i201  = 1.0f / 80802.0f;
    const float i100  = 1.0f / 20000.0f;
    dim3 blk(256);
    float* st = stats;

    // Block 0 @ 1615
    conv1_stats_kernel<<<dim3(51, 13, 2), blk, 0, stream>>>(
        x, w[0], st, 1615, 1615);
    pack_w_kernel<<<dim3(10), blk, 0, stream>>>(w[1], w2p, 16, 1, 1 * 5 * 1 * 512);
    fold_w1_kernel<<<dim3(1), dim3(160), 0, stream>>>(
        w[0], gb[0], st, i1615, w1f, b1f);
    conv12_mfma_kernel<<<dim3(51, 101, 2), blk, 0, stream>>>(
        x, C2, w1f, b1f, w2p, B2, 1615, 1615);
    pool_kernel<16><<<dim3(7, 807, 2), blk, 0, stream>>>(
        C2, P1, gb[1], B2, 8, i1615, 1615, 1615, 807, 807);

    // C2 dead: zero layer-3..10 banks, pack w3/w4 (merged)
    hipMemsetAsync(BK3, 0, 8 * 32 * 160 * sizeof(float), stream);
    pack2_kernel<<<dim3(60), blk, 0, stream>>>(w[2], w[3], w3p, w4p);

    // Block 1 @ 807 (MFMA, TH=8)
    conv3x3_mfma_kernel<16, 32, false, 8><<<dim3(26, 101, 2), blk, 0, stream>>>(
        P1, C3, w3p, nullptr, nullptr, 0.f, SL(3), 807, 807);
    conv3x3_mfma_kernel<32, 32, true, 8><<<dim3(26, 101, 2), blk, 0, stream>>>(
        C3, C4, w4p, gb[2], SL(3), i807, SL(4), 807, 807);
    pool_kernel<32><<<dim3(7, 403, 2), blk, 0, stream>>>(
        C4, P2, gb[3], SL(4), 32, i807, 807, 807, 403, 403);

    // pack w5..w10 (merged)
    pack6_kernel<<<dim3(880), blk, 0, stream>>>(
        w[4], w[5], w[6], w[7], w[8], w[9],
        w5p, w6p, w7p, w8p, w9p, w10p);

    // Block 2 @ 403 (TH=8)
    conv3x3_mfma_kernel<32, 48, false, 8><<<dim3(13, 51, 2), blk, 0, stream>>>(
        P2, C5, w5p, nullptr, nullptr, 0.f, SL(5), 403, 403);
    conv3x3_mfma_kernel<48, 48, true, 8><<<dim3(13, 51, 2), blk, 0, stream>>>(
        C5, C6, w6p, gb[4], SL(5), i403, SL(6), 403, 403);
    pool_kernel<48><<<dim3(5, 201, 2), blk, 0, stream>>>(
        C6, P3, gb[5], SL(6), 32, i403, 403, 403, 201, 201);

    // Block 3 @ 201 (TH=4: 2x blocks for occupancy on small grids)
    conv3x3_mfma_kernel<48, 64, false, 4><<<dim3(7, 51, 2), blk, 0, stream>>>(
        P3, C7, w7p, nullptr, nullptr, 0.f, SL(7), 201, 201);
    conv3x3_mfma_kernel<64, 64, true, 4><<<dim3(7, 51, 2), blk, 0, stream>>>(
        C7, C8, w8p, gb[6], SL(7), i201, SL(8), 201, 201);
    pool_kernel<64><<<dim3(4, 100, 2), blk, 0, stream>>>(
        C8, P4, gb[7], SL(8), 32, i201, 201, 201, 100, 100);

    // Block 4 @ 100 (TH=4)
    conv3x3_mfma_kernel<64, 80, false, 4><<<dim3(4, 25, 2), blk, 0, stream>>>(
        P4, C9, w9p, nullptr, nullptr, 0.f, SL(9), 100, 100);
    conv3x3_mfma_kernel<80, 80, true, 4><<<dim3(4, 25, 2), blk, 0, stream>>>(
        C9, C10, w10p, gb[8], SL(9), i100, SL(10), 100, 100);

    // Tail
    tail_reduce_kernel<<<dim3(10, 2), blk, 0, stream>>>(
        C10, gb[9], SL(10), i100, hbuf);
    head_kernel<<<dim3(1), dim3(128), 0, stream>>>(
        hbuf, bn_gb, lin_w, lin_b, outp);

    (void)in_sizes; (void)n_in; (void)out_size; (void)ws_size;
}